// Round 1
// baseline (264.970 us; speedup 1.0000x reference)
//
#include <hip/hip_runtime.h>

// B=128, A=512, N=256.
// out[b,a,n] = r_ij[b,a,n] + f(zi, zj); f has only 89*89 distinct values.
// R5: fuse table build into the main kernel (drop build_tab dispatch + its
//     graph dependency + per-block 16KB tabg L2 reads). Issue ALL global
//     loads FIRST (2x an + 16x 16B nt loads), then build the f16 table with
//     pure VALU while those loads are in flight, then sync and consume in
//     issue order. Table math identical to the old build_tab (absmax must
//     stay 0.03125).

#define BB 128
#define AA 512
#define NN 256
#define ROWS 32            // a-rows per block -> grid = 2048
#define TPB 256
#define TABN 8192          // 90*90=8100 rounded up

typedef int   v4i __attribute__((ext_vector_type(4)));
typedef float v4f __attribute__((ext_vector_type(4)));

__device__ __forceinline__ float tab_entry(int idx) {
    int zi = idx / 90, zj = idx - zi * 90;
    float p = fmaxf((float)(zi * zj), 1.0f);
    float s = fmaxf((float)(zi + zj), 1.0f);
    const float c = -0.05f * 2.718281828459045f;
    return __expf(c * __powf(p, 1.01f) / __powf(s, 1.1f));
}

__global__ __launch_bounds__(TPB, 4) void RAN_72567767433723_kernel(
    const float* __restrict__ an,
    const int*   __restrict__ nbrs,
    const float* __restrict__ rij,
    float*       __restrict__ out)
{
    __shared__ _Float16       tab[TABN];  // 16384 B
    __shared__ unsigned short zz[AA];     //  1024 B -> 17408 B total

    const int tid      = threadIdx.x;
    const int b        = blockIdx.x >> 4;            // 16 blocks per batch
    const int row_base = (blockIdx.x & 15) * ROWS;

    const int w  = tid >> 6;             // wave id 0..3
    const int l  = tid & 63;             // float4 slot in row (N/4 = 64)
    const int a0 = row_base + w;         // wave w: rows a0 + 4*it, it=0..7
    const size_t base = ((size_t)(b * AA + a0)) * NN + (size_t)(l * 4);

    // Phase 0a: issue the an loads first (oldest in the vmem FIFO, so the
    // zz writes below only need vmcnt(16), not a full drain).
    float anv[AA / TPB];
    #pragma unroll
    for (int i = 0; i < AA / TPB; ++i)
        anv[i] = an[b * AA + i * TPB + tid];

    // Phase 0b: issue ALL 16 big global loads (16 x 16B/lane in flight).
    v4i nb[8]; v4f rj[8];
    #pragma unroll
    for (int it = 0; it < 8; ++it) {
        const size_t e = base + (size_t)(it * 4) * NN;
        nb[it] = __builtin_nontemporal_load((const v4i*)(nbrs + e));
        rj[it] = __builtin_nontemporal_load((const v4f*)(rij + e));
    }

    // Phase 1: build the f16 table with pure VALU — overlaps the in-flight
    // global loads (no vm dependency). ~2k cycles/wave, hidden under ~32us
    // of memory per CU.
    #pragma unroll 4
    for (int i = 0; i < TABN / TPB; ++i) {
        int idx = i * TPB + tid;
        tab[idx] = (_Float16)tab_entry(idx);
    }
    #pragma unroll
    for (int i = 0; i < AA / TPB; ++i)
        zz[i * TPB + tid] = (unsigned short)(int)(anv[i] + 0.5f);
    __syncthreads();

    // Row-base table offsets (wave-uniform LDS broadcasts).
    int tb[8];
    #pragma unroll
    for (int it = 0; it < 8; ++it)
        tb[it] = (int)zz[a0 + it * 4] * 90;

    // Phase 2: LDS gathers + stores, consuming loads in issue order.
    #pragma unroll
    for (int it = 0; it < 8; ++it) {
        const size_t e = base + (size_t)(it * 4) * NN;
        v4f o;
        o.x = rj[it].x + (float)tab[tb[it] + (int)zz[nb[it].x]];
        o.y = rj[it].y + (float)tab[tb[it] + (int)zz[nb[it].y]];
        o.z = rj[it].z + (float)tab[tb[it] + (int)zz[nb[it].z]];
        o.w = rj[it].w + (float)tab[tb[it] + (int)zz[nb[it].w]];
        __builtin_nontemporal_store(o, (v4f*)(out + e));
    }
}

extern "C" void kernel_launch(void* const* d_in, const int* in_sizes, int n_in,
                              void* d_out, int out_size, void* d_ws, size_t ws_size,
                              hipStream_t stream) {
    const float* an  = (const float*)d_in[0];
    const int*   nbr = (const int*)d_in[1];
    const float* rij = (const float*)d_in[2];
    float*       o   = (float*)d_out;

    const int grid = (BB * AA) / ROWS;   // 2048
    RAN_72567767433723_kernel<<<grid, TPB, 0, stream>>>(an, nbr, rij, o);
}

// Round 3
// 163.789 us; speedup vs baseline: 1.6178x; 1.6178x over previous
//
#include <hip/hip_runtime.h>

// B=128, A=512, N=256.
// out[b,a,n] = r_ij[b,a,n] + f(zi, zj); f has only 89*89 distinct values.
// R7 (= R6 re-run after infra failure, with hardened intrinsics):
//     single-kernel fusion (no build_tab dispatch, no graph edge, no
//     per-block tabg reads); table built per-block with native
//     v_log_f32/v_exp_f32 chains instead of R5's precise ocml __powf
//     (which was hundreds of insts and made the kernel VALU-bound at 94%):
//       f = exp2( K * exp2(1.01*log2(p) - 1.1*log2(s)) ), K = -0.05*E*log2(e)
//     ~10 VALU ops/entry, hidden under the in-flight global loads. Table is
//     f16-quantized anyway, so accuracy is unchanged (absmax 0.03125).
//     __builtin_amdgcn_exp2f/__builtin_amdgcn_logf pin the lowering to the
//     single-instruction HW transcendentals regardless of header version.

#define BB 128
#define AA 512
#define NN 256
#define ROWS 32            // a-rows per block -> grid = 2048
#define TPB 256
#define TABN 8192          // 90*90=8100 rounded up

typedef int   v4i __attribute__((ext_vector_type(4)));
typedef float v4f __attribute__((ext_vector_type(4)));

__device__ __forceinline__ float tab_entry_fast(int idx) {
    int zi = idx / 90, zj = idx - zi * 90;
    float p = fmaxf((float)(zi * zj), 1.0f);
    float s = fmaxf((float)(zi + zj), 1.0f);
    // p^1.01 / s^1.1 = exp2(1.01*log2(p) - 1.1*log2(s))
    float t = __builtin_amdgcn_exp2f(
        fmaf(1.01f, __builtin_amdgcn_logf(p),
             -1.1f * __builtin_amdgcn_logf(s)));
    // exp(-0.05*E * t) = exp2(K * t), K = -0.05*E*log2(e)
    const float K = -0.19608258700670691f;
    return __builtin_amdgcn_exp2f(K * t);
}

__global__ __launch_bounds__(TPB, 4) void RAN_72567767433723_kernel(
    const float* __restrict__ an,
    const int*   __restrict__ nbrs,
    const float* __restrict__ rij,
    float*       __restrict__ out)
{
    __shared__ _Float16       tab[TABN];  // 16384 B
    __shared__ unsigned short zz[AA];     //  1024 B -> 17408 B total

    const int tid      = threadIdx.x;
    const int b        = blockIdx.x >> 4;            // 16 blocks per batch
    const int row_base = (blockIdx.x & 15) * ROWS;

    const int w  = tid >> 6;             // wave id 0..3
    const int l  = tid & 63;             // float4 slot in row (N/4 = 64)
    const int a0 = row_base + w;         // wave w: rows a0 + 4*it, it=0..7
    const size_t base = ((size_t)(b * AA + a0)) * NN + (size_t)(l * 4);

    // Phase 0a: issue the an loads first (oldest in the vmem FIFO).
    float anv[AA / TPB];
    #pragma unroll
    for (int i = 0; i < AA / TPB; ++i)
        anv[i] = an[b * AA + i * TPB + tid];

    // Phase 0b: issue ALL 16 big global loads (16 x 16B/lane in flight).
    v4i nb[8]; v4f rj[8];
    #pragma unroll
    for (int it = 0; it < 8; ++it) {
        const size_t e = base + (size_t)(it * 4) * NN;
        nb[it] = __builtin_nontemporal_load((const v4i*)(nbrs + e));
        rj[it] = __builtin_nontemporal_load((const v4f*)(rij + e));
    }

    // Phase 1: build the f16 table with cheap native-transcendental VALU —
    // overlaps the in-flight global loads (no vm dependency).
    #pragma unroll 4
    for (int i = 0; i < TABN / TPB; ++i) {
        int idx = i * TPB + tid;
        tab[idx] = (_Float16)tab_entry_fast(idx);
    }
    #pragma unroll
    for (int i = 0; i < AA / TPB; ++i)
        zz[i * TPB + tid] = (unsigned short)(int)(anv[i] + 0.5f);
    __syncthreads();

    // Row-base table offsets (wave-uniform LDS broadcasts).
    int tb[8];
    #pragma unroll
    for (int it = 0; it < 8; ++it)
        tb[it] = (int)zz[a0 + it * 4] * 90;

    // Phase 2: LDS gathers + stores, consuming loads in issue order.
    #pragma unroll
    for (int it = 0; it < 8; ++it) {
        const size_t e = base + (size_t)(it * 4) * NN;
        v4f o;
        o.x = rj[it].x + (float)tab[tb[it] + (int)zz[nb[it].x]];
        o.y = rj[it].y + (float)tab[tb[it] + (int)zz[nb[it].y]];
        o.z = rj[it].z + (float)tab[tb[it] + (int)zz[nb[it].z]];
        o.w = rj[it].w + (float)tab[tb[it] + (int)zz[nb[it].w]];
        __builtin_nontemporal_store(o, (v4f*)(out + e));
    }
}

extern "C" void kernel_launch(void* const* d_in, const int* in_sizes, int n_in,
                              void* d_out, int out_size, void* d_ws, size_t ws_size,
                              hipStream_t stream) {
    const float* an  = (const float*)d_in[0];
    const int*   nbr = (const int*)d_in[1];
    const float* rij = (const float*)d_in[2];
    float*       o   = (float*)d_out;

    const int grid = (BB * AA) / ROWS;   // 2048
    RAN_72567767433723_kernel<<<grid, TPB, 0, stream>>>(an, nbr, rij, o);
}